// Round 10
// baseline (694.202 us; speedup 1.0000x reference)
//
#include <hip/hip_runtime.h>

#define KBIN 224      // interpolation bins
#define TSTRIDE 68    // packed-table row stride in uints
#define TPSZ  15232   // uints per packed table (= KBIN*TSTRIDE)
#define FBASE 15232   // uint index of f-chunk region in conv LDS
#define NWG 512

typedef _Float16 half2v __attribute__((ext_vector_type(2)));

__device__ __forceinline__ float ssp(float x) {
    // softplus(x) - ln2, numerically stable
    return fmaxf(x, 0.0f) + log1pf(expf(-fabsf(x))) - 0.69314718055994531f;
}

__device__ __forceinline__ float bclane(float v, int l) {
    return __builtin_bit_cast(float, __builtin_amdgcn_readlane(__builtin_bit_cast(int, v), l));
}

// out[lane] = sum_f bclane(x,f) * WT[lane][f]; WT swizzled, b128 conflict-free
__device__ __forceinline__ float matvec64(const float* __restrict__ ldsA, int base, float xv, int lane) {
    float a0 = 0.f, a1 = 0.f, a2 = 0.f, a3 = 0.f;
    #pragma unroll
    for (int gg = 0; gg < 16; ++gg) {
        const float4 w = *(const float4*)&ldsA[base + lane*64 + (((gg + lane) & 15) << 2)];
        a0 += bclane(xv, gg*4+0) * w.x;
        a1 += bclane(xv, gg*4+1) * w.y;
        a2 += bclane(xv, gg*4+2) * w.z;
        a3 += bclane(xv, gg*4+3) * w.w;
    }
    return (a0 + a1) + (a2 + a3);
}

__device__ __forceinline__ void stageWT(float* __restrict__ lds, int base, const float* __restrict__ W, int tid) {
    for (int s = tid; s < 4096; s += 512) {
        int f = s >> 6, g = s & 63;
        lds[base + g*64 + ((((f >> 2) + g) & 15) << 2) + (f & 3)] = W[s];
    }
}

// contention-free grid barrier: per-wg arrival flags + one release word per slot.
// Co-residency of all NWG wgs is guaranteed by __launch_bounds__(512,4) + 77312B LDS
// (2 wgs/CU x 256 CUs = 512; R8 ran this exact shape as a normal launch).
__device__ __forceinline__ void gbar(unsigned int* __restrict__ flags, unsigned int* __restrict__ rel,
                                     int slot, int wg, int tid) {
    __syncthreads();
    if (tid == 0) {
        __threadfence();
        __hip_atomic_store(&flags[slot*NWG + wg], 1u, __ATOMIC_RELEASE, __HIP_MEMORY_SCOPE_AGENT);
    }
    if (wg == 0) {
        while (__hip_atomic_load(&flags[slot*NWG + tid], __ATOMIC_ACQUIRE, __HIP_MEMORY_SCOPE_AGENT) == 0u)
            __builtin_amdgcn_s_sleep(1);
        __syncthreads();
        if (tid == 0)
            __hip_atomic_store(&rel[slot], 1u, __ATOMIC_RELEASE, __HIP_MEMORY_SCOPE_AGENT);
    }
    if (tid == 0) {
        while (__hip_atomic_load(&rel[slot], __ATOMIC_ACQUIRE, __HIP_MEMORY_SCOPE_AGENT) == 0u)
            __builtin_amdgcn_s_sleep(1);
        __threadfence();
    }
    __syncthreads();
}

__global__ __launch_bounds__(512, 4) void schnet_fused(
    const float* __restrict__ emb, const float* __restrict__ dists,
    const float* __restrict__ in2f,
    const float* __restrict__ fw1, const float* __restrict__ fb1,
    const float* __restrict__ fw2, const float* __restrict__ fb2,
    const float* __restrict__ f2o, const float* __restrict__ f2b,
    const float* __restrict__ dw,  const float* __restrict__ db,
    const float* __restrict__ aw1, const float* __restrict__ ab1,
    const float* __restrict__ aw2, const float* __restrict__ ab2,
    float* __restrict__ out,
    unsigned int* __restrict__ Tp_g, unsigned short* __restrict__ f16w,
    float* __restrict__ x_buf, float* __restrict__ y_ws,
    unsigned int* __restrict__ flags, unsigned int* __restrict__ rel)
{
    __shared__ unsigned int ldsu[FBASE + 4096];   // 77312 B -> 2 wgs/CU
    float* lds = (float*)ldsu;
    const int wg = blockIdx.x, tid = threadIdx.x;
    const int wave = tid >> 6, lane = tid & 63;
    // conv mapping
    const int jc = wg & 3, it = (wg >> 2) & 31, b = wg >> 7;
    const int i0 = it * 16;
    // row mapping (waves 0..3 handle one row each)
    const int row = wg*4 + wave;
    const size_t ro = (size_t)row*64 + lane;

    // ======== P0: f0 rows (waves 0-3 of all wgs) + table build/pack (waves 4-7 of wgs<168) ========
    stageWT(lds, 0, in2f, tid);
    const bool tabwg = (wg < 168);
    const int tt = wg / 56;
    if (tabwg) {
        const float* fw1t = fw1 + tt*25*64;
        const float* fw2t = fw2 + tt*64*64;
        for (int s = tid; s < 1600; s += 512) lds[4096 + s] = fw1t[s];
        for (int s = tid; s < 4096; s += 512) lds[5696 + s] = fw2t[s];
        if (tid < 64) { lds[9792 + tid] = fb1[tt*64 + tid]; lds[9856 + tid] = fb2[tt*64 + tid]; }
    }
    __syncthreads();     // uniform: staging done
    if (wave < 4) {
        float xv = emb[ro];
        float fo = matvec64(lds, 0, xv, lane);
        f16w[ro] = __builtin_bit_cast(unsigned short, (_Float16)fo);
    } else if (tabwg) {
        int k = (wg % 56)*4 + (wave - 4);   // bin 0..223
        float T2[2];
        #pragma unroll
        for (int e = 0; e < 2; ++e) {
            float dk = (float)(k + e) * (5.0f/224.0f);
            float h1 = lds[9792 + lane];
            for (int r = 0; r < 25; ++r) {
                float sr = dk - (float)r * (5.0f/24.0f);
                h1 += expf(-10.0f*sr*sr) * lds[4096 + r*64 + lane];
            }
            float u = ssp(h1);
            float T = lds[9856 + lane];
            #pragma unroll
            for (int gg = 0; gg < 64; ++gg)
                T += bclane(u, gg) * lds[5696 + gg*64 + lane];
            T2[e] = T;
        }
        // wave-private LDS scratch; same-wave write->read is ordered by lgkmcnt (no barrier needed)
        float* sc = &lds[9920 + (wave - 4)*128];
        sc[lane] = T2[0];
        sc[64 + lane] = T2[1];
        if (lane < 16) {
            float4 A  = *(const float4*)&sc[lane*4];
            float4 Bv = *(const float4*)&sc[64 + lane*4];
            half2v t01 = { (_Float16)A.x, (_Float16)A.y };
            half2v t23 = { (_Float16)A.z, (_Float16)A.w };
            half2v d01 = { (_Float16)(Bv.x - A.x), (_Float16)(Bv.y - A.y) };
            half2v d23 = { (_Float16)(Bv.z - A.z), (_Float16)(Bv.w - A.w) };
            uint4 o;
            o.x = __builtin_bit_cast(unsigned int, t01);
            o.y = __builtin_bit_cast(unsigned int, t23);
            o.z = __builtin_bit_cast(unsigned int, d01);
            o.w = __builtin_bit_cast(unsigned int, d23);
            *(uint4*)&Tp_g[(size_t)tt*TPSZ + k*TSTRIDE + lane*4] = o;
        }
    }
    gbar(flags, rel, 0, wg, tid);

    for (int t = 0; t < 3; ++t) {
        // ================= conv phase (R8 body) =================
        const unsigned int* Tp = Tp_g + (size_t)t*TPSZ;
        for (int s = tid; s < TPSZ/4; s += 512)
            ((uint4*)ldsu)[s] = ((const uint4*)Tp)[s];
        for (int s = tid; s < 2048; s += 512) {
            int j = s >> 4, fq = s & 15;
            const unsigned int* src = (const unsigned int*)&f16w[((size_t)b*512 + jc*128 + j)*64 + fq*4];
            int jp = j >> 1;
            unsigned int* dst = &ldsu[FBASE + fq*256 + (((jp + fq) & 63) << 2) + (j & 1)*2];
            dst[0] = src[0]; dst[1] = src[1];
        }
        __syncthreads();
        {
            const int g = lane >> 4, fq = lane & 15;
            const int il = wave*2 + (g >> 1);
            const int jh = g & 1;
            const float4* drow4 = (const float4*)&dists[((size_t)(b*512 + i0 + il))*512 + jc*128 + jh*64];
            const unsigned int* Tbase = ldsu + fq*4;
            const unsigned int* ftb = ldsu + FBASE + fq*256;
            const float scale = 224.0f/5.0f;
            float a0 = 0.f, a1 = 0.f, a2 = 0.f, a3 = 0.f;
            float fr0[4]; uint4 tp0[4];
            {
                float4 dv = drow4[0];
                float dd[4] = {dv.x, dv.y, dv.z, dv.w};
                #pragma unroll
                for (int u = 0; u < 4; ++u) {
                    float tv = fminf(fmaxf(dd[u], 0.0f)*scale, 223.999f);
                    int k = (int)tv; fr0[u] = tv - (float)k;
                    tp0[u] = *(const uint4*)&Tbase[k*TSTRIDE];
                }
            }
            float4 dvK = drow4[1];
            uint4 fA0 = *(const uint4*)&ftb[((jh*32 + 0 + fq) & 63) << 2];
            uint4 fB0 = *(const uint4*)&ftb[((jh*32 + 1 + fq) & 63) << 2];
            #pragma unroll 2
            for (int j4 = 0; j4 < 16; ++j4) {
                float4 dvL = (j4 < 14) ? drow4[j4 + 2] : dvK;
                float fr1[4]; uint4 tp1[4];
                {
                    float dd[4] = {dvK.x, dvK.y, dvK.z, dvK.w};
                    #pragma unroll
                    for (int u = 0; u < 4; ++u) {
                        float tv = fminf(fmaxf(dd[u], 0.0f)*scale, 223.999f);
                        int k = (int)tv; fr1[u] = tv - (float)k;
                        tp1[u] = *(const uint4*)&Tbase[k*TSTRIDE];
                    }
                }
                int jpn = jh*32 + ((j4 + 1) & 15)*2;
                uint4 fA1 = *(const uint4*)&ftb[((jpn + fq) & 63) << 2];
                uint4 fB1 = *(const uint4*)&ftb[((jpn + 1 + fq) & 63) << 2];
                unsigned int fl_[8] = {fA0.x, fA0.y, fA0.z, fA0.w, fB0.x, fB0.y, fB0.z, fB0.w};
                #pragma unroll
                for (int u = 0; u < 4; ++u) {
                    _Float16 ah = (_Float16)fr0[u];
                    half2v av = { ah, ah };
                    half2v W01 = __builtin_bit_cast(half2v, tp0[u].z)*av + __builtin_bit_cast(half2v, tp0[u].x);
                    half2v W23 = __builtin_bit_cast(half2v, tp0[u].w)*av + __builtin_bit_cast(half2v, tp0[u].y);
                    half2v f01 = __builtin_bit_cast(half2v, fl_[u*2]);
                    half2v f23 = __builtin_bit_cast(half2v, fl_[u*2+1]);
                    a0 += (float)W01[0] * (float)f01[0];
                    a1 += (float)W01[1] * (float)f01[1];
                    a2 += (float)W23[0] * (float)f23[0];
                    a3 += (float)W23[1] * (float)f23[1];
                }
                dvK = dvL;
                fr0[0]=fr1[0]; fr0[1]=fr1[1]; fr0[2]=fr1[2]; fr0[3]=fr1[3];
                tp0[0]=tp1[0]; tp0[1]=tp1[1]; tp0[2]=tp1[2]; tp0[3]=tp1[3];
                fA0 = fA1; fB0 = fB1;
            }
            int c8 = jc*2 + jh;
            float4 acc; acc.x = a0; acc.y = a1; acc.z = a2; acc.w = a3;
            *(float4*)&y_ws[((size_t)c8*2048 + b*512 + i0 + il)*64 + fq*4] = acc;
        }
        gbar(flags, rel, 1 + 2*t, wg, tid);

        if (t < 2) {
            // ================= pre(t+1) =================
            int tn = t + 1;
            stageWT(lds, 0, in2f + tn*4096, tid);
            stageWT(lds, 4096, f2o + t*4096, tid);
            stageWT(lds, 8192, dw + t*4096, tid);
            if (tid < 64) { lds[12288 + tid] = f2b[t*64 + tid]; lds[12352 + tid] = db[t*64 + tid]; }
            __syncthreads();
            if (wave < 4) {
                float y = 0.0f;
                #pragma unroll
                for (int c = 0; c < 8; ++c) y += y_ws[(size_t)c*131072 + ro];
                float z = matvec64(lds, 4096, y, lane) + lds[12288 + lane];
                float u = ssp(z);
                float y3 = matvec64(lds, 8192, u, lane) + lds[12352 + lane];
                const float* xin = (tn == 1) ? emb : x_buf;
                float xv = xin[ro] + y3;
                x_buf[ro] = xv;
                float fo = matvec64(lds, 0, xv, lane);
                f16w[ro] = __builtin_bit_cast(unsigned short, (_Float16)fo);
            }
            gbar(flags, rel, 2 + 2*t, wg, tid);
        }
    }

    // ================= final =================
    stageWT(lds, 0, f2o + 2*4096, tid);
    stageWT(lds, 4096, dw + 2*4096, tid);
    for (int s = tid; s < 4096; s += 512) {
        int f = s >> 6, r = s & 63;
        lds[8192 + r*64 + ((((f >> 2) + r) & 15) << 2) + (f & 3)] = aw1[f*32 + (r & 31)];
    }
    if (tid < 64) {
        lds[12288 + tid] = f2b[2*64 + tid];
        lds[12352 + tid] = db[2*64 + tid];
        lds[12416 + tid] = ab1[tid & 31];
        lds[12480 + tid] = aw2[tid & 31];
    }
    __syncthreads();
    if (wave < 4) {
        float y = 0.0f;
        #pragma unroll
        for (int c = 0; c < 8; ++c) y += y_ws[(size_t)c*131072 + ro];
        float z = matvec64(lds, 0, y, lane) + lds[12288 + lane];
        float u = ssp(z);
        float y3 = matvec64(lds, 4096, u, lane) + lds[12352 + lane];
        float x3 = x_buf[ro] + y3;
        float s1 = matvec64(lds, 8192, x3, lane) + lds[12416 + lane];
        float h = ssp(s1) * lds[12480 + lane];
        float sum = h;
        #pragma unroll
        for (int m = 1; m < 64; m <<= 1)
            sum += __shfl_xor(sum, m, 64);
        if (lane == 0) out[row] = ab2[0] + 0.5f*sum;   // lanes duplicate the 32-dim h twice
    }
}

extern "C" void kernel_launch(void* const* d_in, const int* in_sizes, int n_in,
                              void* d_out, int out_size, void* d_ws, size_t ws_size,
                              hipStream_t stream) {
    const float* emb  = (const float*)d_in[0];
    const float* dist = (const float*)d_in[1];
    const float* in2f = (const float*)d_in[2];
    const float* fw1  = (const float*)d_in[3];
    const float* fb1  = (const float*)d_in[4];
    const float* fw2  = (const float*)d_in[5];
    const float* fb2  = (const float*)d_in[6];
    const float* f2o  = (const float*)d_in[7];
    const float* f2b  = (const float*)d_in[8];
    const float* dwp  = (const float*)d_in[9];
    const float* dbp  = (const float*)d_in[10];
    const float* aw1  = (const float*)d_in[11];
    const float* ab1  = (const float*)d_in[12];
    const float* aw2  = (const float*)d_in[13];
    const float* ab2  = (const float*)d_in[14];
    float* out = (float*)d_out;
    float* ws = (float*)d_ws;
    unsigned int* Tp_g = (unsigned int*)ws;                // 3*15232 = 45696 uints
    unsigned short* f16w = (unsigned short*)(ws + 45696);  // 65536 float slots
    float* x_buf = ws + 45696 + 65536;                     // 131072 floats
    float* y_ws  = x_buf + 131072;                         // 8*131072 floats
    unsigned int* flags = (unsigned int*)(y_ws + 1048576); // 6*512 + 6 uints
    unsigned int* rel   = flags + 6*NWG;

    hipMemsetAsync(flags, 0, (6*NWG + 6)*sizeof(unsigned int), stream);

    hipLaunchKernelGGL(schnet_fused, dim3(NWG), dim3(512), 0, stream,
        emb, dist, in2f, fw1, fb1, fw2, fb2, f2o, f2b, dwp, dbp,
        aw1, ab1, aw2, ab2, out, Tp_g, f16w, x_buf, y_ws, flags, rel);
}

// Round 11
// 247.309 us; speedup vs baseline: 2.8070x; 2.8070x over previous
//
#include <hip/hip_runtime.h>

#define KBIN 224      // interpolation bins
#define TSTRIDE 68    // packed-table row stride in uints
#define TPSZ  15232   // uints per packed table (= KBIN*TSTRIDE)
#define FBASE 15232   // uint index of f-chunk region in conv LDS

// flag indices (uints): [0..767] pre (t*256+wg), [768..851] table, [852..1363] conv(t==2)
#define FL_PRE(t,w)  ((t)*256 + (w))
#define FL_TAB(i)    (768 + (i))
#define FL_CONV(c)   (852 + (c))
#define NFLAGS 1364

typedef _Float16 half2v __attribute__((ext_vector_type(2)));

__device__ __forceinline__ float ssp(float x) {
    // softplus(x) - ln2, numerically stable
    return fmaxf(x, 0.0f) + log1pf(expf(-fabsf(x))) - 0.69314718055994531f;
}

__device__ __forceinline__ float bclane(float v, int l) {
    return __builtin_bit_cast(float, __builtin_amdgcn_readlane(__builtin_bit_cast(int, v), l));
}

__device__ __forceinline__ void spinflag(unsigned int* f) {
    while (__hip_atomic_load(f, __ATOMIC_ACQUIRE, __HIP_MEMORY_SCOPE_AGENT) == 0u)
        __builtin_amdgcn_s_sleep(4);
    __threadfence();
}

__device__ __forceinline__ void setflag_block(unsigned int* f, int tid) {
    __syncthreads();                // drains this block's stores (vmcnt 0 before barrier)
    if (tid == 0) {
        __threadfence();
        __hip_atomic_store(f, 1u, __ATOMIC_RELEASE, __HIP_MEMORY_SCOPE_AGENT);
    }
}

// out[lane] = sum_f bclane(x,f) * WT[lane][f]; WT swizzled, b128 conflict-free
__device__ __forceinline__ float matvec64(const float* __restrict__ ldsA, int base, float xv, int lane) {
    float a0 = 0.f, a1 = 0.f, a2 = 0.f, a3 = 0.f;
    #pragma unroll
    for (int gg = 0; gg < 16; ++gg) {
        const float4 w = *(const float4*)&ldsA[base + lane*64 + (((gg + lane) & 15) << 2)];
        a0 += bclane(xv, gg*4+0) * w.x;
        a1 += bclane(xv, gg*4+1) * w.y;
        a2 += bclane(xv, gg*4+2) * w.z;
        a3 += bclane(xv, gg*4+3) * w.w;
    }
    return (a0 + a1) + (a2 + a3);
}

__device__ __forceinline__ void stageWT(float* __restrict__ lds, int base, const float* __restrict__ W, int tid) {
    for (int s = tid; s < 4096; s += 512) {
        int f = s >> 6, g = s & 63;
        lds[base + g*64 + ((((f >> 2) + g) & 15) << 2) + (f & 3)] = W[s];
    }
}

// K(t): wgs [0,256): pre(t).  t==0: wgs [256,340): table build+pack.
//       wgs [convbase, convbase+512): conv(t), flag-guarded (waits only on LOWER wg ids).
//       t==2: wgs [768,1024): final, waits on conv flags.
__global__ __launch_bounds__(512, 4) void schnet_k(
    int t,
    const float* __restrict__ emb, const float* __restrict__ dists,
    const float* __restrict__ in2f,
    const float* __restrict__ fw1, const float* __restrict__ fb1,
    const float* __restrict__ fw2, const float* __restrict__ fb2,
    const float* __restrict__ f2o, const float* __restrict__ f2b,
    const float* __restrict__ dw,  const float* __restrict__ db,
    const float* __restrict__ aw1, const float* __restrict__ ab1,
    const float* __restrict__ aw2, const float* __restrict__ ab2,
    float* __restrict__ out,
    unsigned int* __restrict__ Tp_g, unsigned short* __restrict__ f16w,
    float* __restrict__ x_buf, float* __restrict__ y_ws,
    unsigned int* __restrict__ flags)
{
    __shared__ unsigned int ldsu[FBASE + 4096];   // 77312 B
    float* lds = (float*)ldsu;
    const int wg = blockIdx.x, tid = threadIdx.x;
    const int wave = tid >> 6, lane = tid & 63;
    const int convbase = (t == 0) ? 340 : 256;

    if (wg < 256) {
        // ================= pre(t): one row per wave =================
        stageWT(lds, 0, in2f + t*4096, tid);
        if (t > 0) {
            stageWT(lds, 4096, f2o + (t-1)*4096, tid);
            stageWT(lds, 8192, dw + (t-1)*4096, tid);
            if (tid < 64) { lds[12288 + tid] = f2b[(t-1)*64 + tid]; lds[12352 + tid] = db[(t-1)*64 + tid]; }
        }
        __syncthreads();
        int row = wg*8 + wave;
        size_t ro = (size_t)row*64 + lane;
        float xv;
        if (t == 0) {
            xv = emb[ro];
        } else {
            float y = 0.0f;
            #pragma unroll
            for (int c = 0; c < 8; ++c) y += y_ws[(size_t)c*131072 + ro];
            float z = matvec64(lds, 4096, y, lane) + lds[12288 + lane];
            float u = ssp(z);
            float y3 = matvec64(lds, 8192, u, lane) + lds[12352 + lane];
            const float* xin = (t == 1) ? emb : x_buf;
            xv = xin[ro] + y3;
            x_buf[ro] = xv;
        }
        float fo = matvec64(lds, 0, xv, lane);
        f16w[ro] = __builtin_bit_cast(unsigned short, (_Float16)fo);
        setflag_block(&flags[FL_PRE(t, wg)], tid);
    } else if (t == 0 && wg < 340) {
        // ================= table build+pack: 28 wgs per tt, 8 bins each =================
        int widx = wg - 256;
        int tt = widx / 28;
        int k = (widx % 28)*8 + wave;        // bin 0..223
        const float* fw1t = fw1 + tt*25*64;
        const float* fw2t = fw2 + tt*64*64;
        for (int s = tid; s < 1600; s += 512) lds[s] = fw1t[s];
        for (int s = tid; s < 4096; s += 512) lds[1600 + s] = fw2t[s];
        if (tid < 64) { lds[5696 + tid] = fb1[tt*64 + tid]; lds[5760 + tid] = fb2[tt*64 + tid]; }
        __syncthreads();
        float T2[2];
        #pragma unroll
        for (int e = 0; e < 2; ++e) {
            float dk = (float)(k + e) * (5.0f/224.0f);
            float h1 = lds[5696 + lane];
            for (int r = 0; r < 25; ++r) {
                float sr = dk - (float)r * (5.0f/24.0f);
                h1 += expf(-10.0f*sr*sr) * lds[r*64 + lane];
            }
            float u = ssp(h1);
            float T = lds[5760 + lane];
            #pragma unroll
            for (int gg = 0; gg < 64; ++gg)
                T += bclane(u, gg) * lds[1600 + gg*64 + lane];
            T2[e] = T;
        }
        float* sc = &lds[5824 + wave*128];   // wave-private scratch (same-wave rd-after-wr: lgkmcnt)
        sc[lane] = T2[0];
        sc[64 + lane] = T2[1];
        if (lane < 16) {
            float4 A  = *(const float4*)&sc[lane*4];
            float4 Bv = *(const float4*)&sc[64 + lane*4];
            half2v t01 = { (_Float16)A.x, (_Float16)A.y };
            half2v t23 = { (_Float16)A.z, (_Float16)A.w };
            half2v d01 = { (_Float16)(Bv.x - A.x), (_Float16)(Bv.y - A.y) };
            half2v d23 = { (_Float16)(Bv.z - A.z), (_Float16)(Bv.w - A.w) };
            uint4 o;
            o.x = __builtin_bit_cast(unsigned int, t01);
            o.y = __builtin_bit_cast(unsigned int, t23);
            o.z = __builtin_bit_cast(unsigned int, d01);
            o.w = __builtin_bit_cast(unsigned int, d23);
            *(uint4*)&Tp_g[(size_t)tt*TPSZ + k*TSTRIDE + lane*4] = o;
        }
        setflag_block(&flags[FL_TAB(widx)], tid);
    } else if (wg < convbase + 512) {
        // ================= conv(t) =================
        const int cwg = wg - convbase;
        const int jc = cwg & 3, it = (cwg >> 2) & 31, b = cwg >> 7;
        const int i0 = it * 16;
        if (t == 0) {          // table rows for tt=0 must exist before the copy
            if (tid < 28) spinflag(&flags[FL_TAB(tid)]);
            __syncthreads();
        }
        const unsigned int* Tp = Tp_g + (size_t)t*TPSZ;
        for (int s = tid; s < TPSZ/4; s += 512)
            ((uint4*)ldsu)[s] = ((const uint4*)Tp)[s];
        // wait for pre of the j-chunk (16 wgs) and of our output i-rows (2 wgs, y_ws WAR)
        if (tid < 16) spinflag(&flags[FL_PRE(t, b*64 + jc*16 + tid)]);
        else if (tid < 18) spinflag(&flags[FL_PRE(t, b*64 + it*2 + (tid - 16))]);
        __syncthreads();
        for (int s = tid; s < 2048; s += 512) {   // transposed f16 f-chunk (128 j)
            int j = s >> 4, fq = s & 15;
            const unsigned int* src = (const unsigned int*)&f16w[((size_t)b*512 + jc*128 + j)*64 + fq*4];
            int jp = j >> 1;
            unsigned int* dst = &ldsu[FBASE + fq*256 + (((jp + fq) & 63) << 2) + (j & 1)*2];
            dst[0] = src[0]; dst[1] = src[1];
        }
        __syncthreads();
        {
            const int g = lane >> 4, fq = lane & 15;
            const int il = wave*2 + (g >> 1);
            const int jh = g & 1;
            const float4* drow4 = (const float4*)&dists[((size_t)(b*512 + i0 + il))*512 + jc*128 + jh*64];
            const unsigned int* Tbase = ldsu + fq*4;
            const unsigned int* ftb = ldsu + FBASE + fq*256;
            const float scale = 224.0f/5.0f;
            float a0 = 0.f, a1 = 0.f, a2 = 0.f, a3 = 0.f;
            float fr0[4]; uint4 tp0[4];
            {
                float4 dv = drow4[0];
                float dd[4] = {dv.x, dv.y, dv.z, dv.w};
                #pragma unroll
                for (int u = 0; u < 4; ++u) {
                    float tv = fminf(fmaxf(dd[u], 0.0f)*scale, 223.999f);
                    int k = (int)tv; fr0[u] = tv - (float)k;
                    tp0[u] = *(const uint4*)&Tbase[k*TSTRIDE];
                }
            }
            float4 dvK = drow4[1];
            uint4 fA0 = *(const uint4*)&ftb[((jh*32 + 0 + fq) & 63) << 2];
            uint4 fB0 = *(const uint4*)&ftb[((jh*32 + 1 + fq) & 63) << 2];
            #pragma unroll 2
            for (int j4 = 0; j4 < 16; ++j4) {
                float4 dvL = (j4 < 14) ? drow4[j4 + 2] : dvK;
                float fr1[4]; uint4 tp1[4];
                {
                    float dd[4] = {dvK.x, dvK.y, dvK.z, dvK.w};
                    #pragma unroll
                    for (int u = 0; u < 4; ++u) {
                        float tv = fminf(fmaxf(dd[u], 0.0f)*scale, 223.999f);
                        int k = (int)tv; fr1[u] = tv - (float)k;
                        tp1[u] = *(const uint4*)&Tbase[k*TSTRIDE];
                    }
                }
                int jpn = jh*32 + ((j4 + 1) & 15)*2;
                uint4 fA1 = *(const uint4*)&ftb[((jpn + fq) & 63) << 2];
                uint4 fB1 = *(const uint4*)&ftb[((jpn + 1 + fq) & 63) << 2];
                unsigned int fl_[8] = {fA0.x, fA0.y, fA0.z, fA0.w, fB0.x, fB0.y, fB0.z, fB0.w};
                #pragma unroll
                for (int u = 0; u < 4; ++u) {
                    _Float16 ah = (_Float16)fr0[u];
                    half2v av = { ah, ah };
                    half2v W01 = __builtin_bit_cast(half2v, tp0[u].z)*av + __builtin_bit_cast(half2v, tp0[u].x);
                    half2v W23 = __builtin_bit_cast(half2v, tp0[u].w)*av + __builtin_bit_cast(half2v, tp0[u].y);
                    half2v f01 = __builtin_bit_cast(half2v, fl_[u*2]);
                    half2v f23 = __builtin_bit_cast(half2v, fl_[u*2+1]);
                    a0 += (float)W01[0] * (float)f01[0];
                    a1 += (float)W01[1] * (float)f01[1];
                    a2 += (float)W23[0] * (float)f23[0];
                    a3 += (float)W23[1] * (float)f23[1];
                }
                dvK = dvL;
                fr0[0]=fr1[0]; fr0[1]=fr1[1]; fr0[2]=fr1[2]; fr0[3]=fr1[3];
                tp0[0]=tp1[0]; tp0[1]=tp1[1]; tp0[2]=tp1[2]; tp0[3]=tp1[3];
                fA0 = fA1; fB0 = fB1;
            }
            int c8 = jc*2 + jh;
            float4 acc; acc.x = a0; acc.y = a1; acc.z = a2; acc.w = a3;
            *(float4*)&y_ws[((size_t)c8*2048 + b*512 + i0 + il)*64 + fq*4] = acc;
        }
        if (t == 2) setflag_block(&flags[FL_CONV(cwg)], tid);
    } else {
        // ================= final (t==2, wgs 768..1023) =================
        int fwg = wg - 768;
        stageWT(lds, 0, f2o + 2*4096, tid);
        stageWT(lds, 4096, dw + 2*4096, tid);
        for (int s = tid; s < 4096; s += 512) {   // aw1^T duplicated to 64 rows, swizzled
            int f = s >> 6, r = s & 63;
            lds[8192 + r*64 + ((((f >> 2) + r) & 15) << 2) + (f & 3)] = aw1[f*32 + (r & 31)];
        }
        if (tid < 64) {
            lds[12288 + tid] = f2b[2*64 + tid];
            lds[12352 + tid] = db[2*64 + tid];
            lds[12416 + tid] = ab1[tid & 31];
            lds[12480 + tid] = aw2[tid & 31];
        }
        // rows [fwg*8, +8) all lie in one (b, it) 16-row tile; wait its 4 conv producers
        int row0 = fwg*8;
        int bb = row0 >> 9, itt = (row0 & 511) >> 4;
        if (tid < 4) spinflag(&flags[FL_CONV(bb*128 + itt*4 + tid)]);
        __syncthreads();
        int row = row0 + wave;
        size_t ro = (size_t)row*64 + lane;
        float y = 0.0f;
        #pragma unroll
        for (int c = 0; c < 8; ++c) y += y_ws[(size_t)c*131072 + ro];
        float z = matvec64(lds, 0, y, lane) + lds[12288 + lane];
        float u = ssp(z);
        float y3 = matvec64(lds, 4096, u, lane) + lds[12352 + lane];
        float x3 = x_buf[ro] + y3;
        float s1 = matvec64(lds, 8192, x3, lane) + lds[12416 + lane];
        float h = ssp(s1) * lds[12480 + lane];
        float sum = h;
        #pragma unroll
        for (int m = 1; m < 64; m <<= 1)
            sum += __shfl_xor(sum, m, 64);
        if (lane == 0) out[row] = ab2[0] + 0.5f*sum;   // lanes duplicate the 32-dim h twice
    }
}

extern "C" void kernel_launch(void* const* d_in, const int* in_sizes, int n_in,
                              void* d_out, int out_size, void* d_ws, size_t ws_size,
                              hipStream_t stream) {
    const float* emb  = (const float*)d_in[0];
    const float* dist = (const float*)d_in[1];
    const float* in2f = (const float*)d_in[2];
    const float* fw1  = (const float*)d_in[3];
    const float* fb1  = (const float*)d_in[4];
    const float* fw2  = (const float*)d_in[5];
    const float* fb2  = (const float*)d_in[6];
    const float* f2o  = (const float*)d_in[7];
    const float* f2b  = (const float*)d_in[8];
    const float* dwp  = (const float*)d_in[9];
    const float* dbp  = (const float*)d_in[10];
    const float* aw1  = (const float*)d_in[11];
    const float* ab1  = (const float*)d_in[12];
    const float* aw2  = (const float*)d_in[13];
    const float* ab2  = (const float*)d_in[14];
    float* out = (float*)d_out;
    float* ws = (float*)d_ws;
    unsigned int* Tp_g = (unsigned int*)ws;                // 3*15232 = 45696 uints
    unsigned short* f16w = (unsigned short*)(ws + 45696);  // 65536 float slots
    float* x_buf = ws + 45696 + 65536;                     // 131072 floats
    float* y_ws  = x_buf + 131072;                         // 8*131072 floats
    unsigned int* flags = (unsigned int*)(y_ws + 1048576); // NFLAGS uints

    hipMemsetAsync(flags, 0, NFLAGS*sizeof(unsigned int), stream);

    for (int t = 0; t < 3; ++t) {
        int grid = (t == 0) ? 852 : (t == 1) ? 768 : 1024;
        hipLaunchKernelGGL(schnet_k, dim3(grid), dim3(512), 0, stream,
            t, emb, dist, in2f, fw1, fb1, fw2, fb2, f2o, f2b, dwp, dbp,
            aw1, ab1, aw2, ab2, out, Tp_g, f16w, x_buf, y_ws, flags);
    }
}

// Round 12
// 82.177 us; speedup vs baseline: 8.4476x; 3.0095x over previous
//
#include <hip/hip_runtime.h>

#define KBIN 224      // interpolation bins
#define TSTRIDE 68    // packed-table row stride in uints
#define TPSZ  15232   // uints per packed table (= KBIN*TSTRIDE)
#define FBASE 15232   // uint index of f-chunk region in conv LDS

typedef _Float16 half2v __attribute__((ext_vector_type(2)));

__device__ __forceinline__ float ssp(float x) {
    // softplus(x) - ln2, numerically stable
    return fmaxf(x, 0.0f) + log1pf(expf(-fabsf(x))) - 0.69314718055994531f;
}

__device__ __forceinline__ float bclane(float v, int l) {
    return __builtin_bit_cast(float, __builtin_amdgcn_readlane(__builtin_bit_cast(int, v), l));
}

// 2-row batched matvec: out{0,1}[lane] = sum_f bclane(x{0,1},f) * WT[lane][f]
// WT swizzled at lds[base + g*64 + ((f/4+g)&15)*4 + (f&3)]; W matrix read ONCE per 2 rows.
__device__ __forceinline__ void matvec64x2(const float* __restrict__ ldsA, int base,
                                           float xv0, float xv1, int lane,
                                           float& o0, float& o1) {
    float a0 = 0.f, a1 = 0.f, b0 = 0.f, b1 = 0.f;
    #pragma unroll
    for (int gg = 0; gg < 16; ++gg) {
        const float4 w = *(const float4*)&ldsA[base + lane*64 + (((gg + lane) & 15) << 2)];
        a0 += bclane(xv0, gg*4+0) * w.x;
        a1 += bclane(xv0, gg*4+1) * w.y;
        a0 += bclane(xv0, gg*4+2) * w.z;
        a1 += bclane(xv0, gg*4+3) * w.w;
        b0 += bclane(xv1, gg*4+0) * w.x;
        b1 += bclane(xv1, gg*4+1) * w.y;
        b0 += bclane(xv1, gg*4+2) * w.z;
        b1 += bclane(xv1, gg*4+3) * w.w;
    }
    o0 = a0 + a1;
    o1 = b0 + b1;
}

__device__ __forceinline__ void stageWT(float* __restrict__ lds, int base, const float* __restrict__ W, int tid) {
    for (int s = tid; s < 4096; s += 512) {
        int f = s >> 6, g = s & 63;
        lds[base + g*64 + ((((f >> 2) + g) & 15) << 2) + (f & 3)] = W[s];
    }
}

// pre: wgs 0..127: TWO rows per wave — (t>0: post-MLP + residual) + f = x@in2f -> f16.
//      wgs 128..211 (t==0 only): build + pack the 3 interp tables to global.
__global__ __launch_bounds__(512) void schnet_pre(
    int t,
    const float* __restrict__ emb,
    float* __restrict__ x_buf,
    const float* __restrict__ y_ws,
    const float* __restrict__ in2f,
    const float* __restrict__ fw1, const float* __restrict__ fb1,
    const float* __restrict__ fw2, const float* __restrict__ fb2,
    const float* __restrict__ f2o, const float* __restrict__ f2b,
    const float* __restrict__ dw,  const float* __restrict__ db,
    unsigned short* __restrict__ f16w, unsigned int* __restrict__ Tp_g)
{
    __shared__ float lds[12544];
    const int wg = blockIdx.x, tid = threadIdx.x;
    const int wave = tid >> 6, lane = tid & 63;
    if (wg < 128) {
        stageWT(lds, 0, in2f + t*4096, tid);
        if (t > 0) {
            stageWT(lds, 4096, f2o + (t-1)*4096, tid);
            stageWT(lds, 8192, dw + (t-1)*4096, tid);
            if (tid < 64) { lds[12288 + tid] = f2b[(t-1)*64 + tid]; lds[12352 + tid] = db[(t-1)*64 + tid]; }
        }
        __syncthreads();
        int row0 = wg*16 + wave*2;           // 2 rows per wave
        size_t ro0 = (size_t)row0*64 + lane;
        size_t ro1 = ro0 + 64;
        float xv0, xv1;
        if (t == 0) {
            xv0 = emb[ro0]; xv1 = emb[ro1];
        } else {
            float y0 = 0.f, y1 = 0.f;
            #pragma unroll
            for (int c = 0; c < 4; ++c) {
                y0 += y_ws[(size_t)c*131072 + ro0];
                y1 += y_ws[(size_t)c*131072 + ro1];
            }
            float z0, z1;
            matvec64x2(lds, 4096, y0, y1, lane, z0, z1);
            float u0 = ssp(z0 + lds[12288 + lane]);
            float u1 = ssp(z1 + lds[12288 + lane]);
            float w0, w1;
            matvec64x2(lds, 8192, u0, u1, lane, w0, w1);
            const float* xin = (t == 1) ? emb : x_buf;
            xv0 = xin[ro0] + w0 + lds[12352 + lane] - lds[12352 + lane] + w0*0.0f;  // placeholder-free below
            xv0 = xin[ro0] + (w0 + lds[12352 + lane]);
            xv1 = xin[ro1] + (w1 + lds[12352 + lane]);
            x_buf[ro0] = xv0;
            x_buf[ro1] = xv1;
        }
        float f0, f1;
        matvec64x2(lds, 0, xv0, xv1, lane, f0, f1);
        f16w[ro0] = __builtin_bit_cast(unsigned short, (_Float16)f0);
        f16w[ro1] = __builtin_bit_cast(unsigned short, (_Float16)f1);
    } else {
        // table build+pack (t==0 launch only): 28 wgs per tt, 8 bins each
        int widx = wg - 128;
        int tt = widx / 28;
        int k = (widx % 28)*8 + wave;        // bin 0..223
        const float* fw1t = fw1 + tt*25*64;
        const float* fw2t = fw2 + tt*64*64;
        for (int s = tid; s < 1600; s += 512) lds[s] = fw1t[s];
        for (int s = tid; s < 4096; s += 512) lds[1600 + s] = fw2t[s];
        if (tid < 64) { lds[5696 + tid] = fb1[tt*64 + tid]; lds[5760 + tid] = fb2[tt*64 + tid]; }
        __syncthreads();
        float T2[2];
        #pragma unroll
        for (int e = 0; e < 2; ++e) {
            float dk = (float)(k + e) * (5.0f/224.0f);
            float h1 = lds[5696 + lane];
            for (int r = 0; r < 25; ++r) {
                float sr = dk - (float)r * (5.0f/24.0f);
                h1 += expf(-10.0f*sr*sr) * lds[r*64 + lane];
            }
            float u = ssp(h1);
            float T = lds[5760 + lane];
            #pragma unroll
            for (int gg = 0; gg < 64; ++gg)
                T += bclane(u, gg) * lds[1600 + gg*64 + lane];
            T2[e] = T;
        }
        float* sc = &lds[5824 + wave*128];   // wave-private scratch (same-wave rd-after-wr: lgkmcnt)
        sc[lane] = T2[0];
        sc[64 + lane] = T2[1];
        if (lane < 16) {
            float4 A  = *(const float4*)&sc[lane*4];
            float4 Bv = *(const float4*)&sc[64 + lane*4];
            half2v t01 = { (_Float16)A.x, (_Float16)A.y };
            half2v t23 = { (_Float16)A.z, (_Float16)A.w };
            half2v d01 = { (_Float16)(Bv.x - A.x), (_Float16)(Bv.y - A.y) };
            half2v d23 = { (_Float16)(Bv.z - A.z), (_Float16)(Bv.w - A.w) };
            uint4 o;
            o.x = __builtin_bit_cast(unsigned int, t01);
            o.y = __builtin_bit_cast(unsigned int, t23);
            o.z = __builtin_bit_cast(unsigned int, d01);
            o.w = __builtin_bit_cast(unsigned int, d23);
            *(uint4*)&Tp_g[(size_t)tt*TPSZ + k*TSTRIDE + lane*4] = o;
        }
    }
}

// conv: y_partial[jc][b*512+i][f] = sum over the wg's 128-j slice of f_j[f] * lerp(T, d_ij)[f]
// 512 wgs: (jc 4) x (it 32) x (b 4); wave covers 2 i's x 2 j-halves; jh halves merged in-wave.
__global__ __launch_bounds__(512, 4) void schnet_conv(
    const float* __restrict__ dists,
    const unsigned short* __restrict__ f16w,
    const unsigned int* __restrict__ Tp,
    float* __restrict__ y_ws)
{
    __shared__ unsigned int ldsu[FBASE + 4096];   // 77312 B -> 2 wgs/CU
    const int wg = blockIdx.x, tid = threadIdx.x;
    const int jc = wg & 3, it = (wg >> 2) & 31, b = wg >> 7;
    const int i0 = it * 16;
    const int wave = tid >> 6, lane = tid & 63;

    // straight copy of pre-packed table
    for (int s = tid; s < TPSZ/4; s += 512)
        ((uint4*)ldsu)[s] = ((const uint4*)Tp)[s];
    // transposed f16 f-chunk (128 j x 64 f16)
    for (int s = tid; s < 2048; s += 512) {
        int j = s >> 4, fq = s & 15;
        const unsigned int* src = (const unsigned int*)&f16w[((size_t)b*512 + jc*128 + j)*64 + fq*4];
        int jp = j >> 1;
        unsigned int* dst = &ldsu[FBASE + fq*256 + (((jp + fq) & 63) << 2) + (j & 1)*2];
        dst[0] = src[0]; dst[1] = src[1];
    }
    __syncthreads();

    const int g = lane >> 4, fq = lane & 15;
    const int il = wave*2 + (g >> 1);        // 0..15
    const int jh = g & 1;                    // j half
    const float4* drow4 = (const float4*)&dists[((size_t)(b*512 + i0 + il))*512 + jc*128 + jh*64];
    const unsigned int* Tbase = ldsu + fq*4;
    const unsigned int* ftb = ldsu + FBASE + fq*256;
    const float scale = 224.0f/5.0f;

    float a0 = 0.f, a1 = 0.f, a2 = 0.f, a3 = 0.f;
    float fr0[4]; uint4 tp0[4];
    {
        float4 dv = drow4[0];
        float dd[4] = {dv.x, dv.y, dv.z, dv.w};
        #pragma unroll
        for (int u = 0; u < 4; ++u) {
            float tv = fminf(fmaxf(dd[u], 0.0f)*scale, 223.999f);
            int k = (int)tv; fr0[u] = tv - (float)k;
            tp0[u] = *(const uint4*)&Tbase[k*TSTRIDE];
        }
    }
    float4 dvK = drow4[1];
    uint4 fA0 = *(const uint4*)&ftb[((jh*32 + 0 + fq) & 63) << 2];
    uint4 fB0 = *(const uint4*)&ftb[((jh*32 + 1 + fq) & 63) << 2];

    #pragma unroll 2
    for (int j4 = 0; j4 < 16; ++j4) {
        float4 dvL = (j4 < 14) ? drow4[j4 + 2] : dvK;
        float fr1[4]; uint4 tp1[4];
        {
            float dd[4] = {dvK.x, dvK.y, dvK.z, dvK.w};
            #pragma unroll
            for (int u = 0; u < 4; ++u) {
                float tv = fminf(fmaxf(dd[u], 0.0f)*scale, 223.999f);
                int k = (int)tv; fr1[u] = tv - (float)k;
                tp1[u] = *(const uint4*)&Tbase[k*TSTRIDE];
            }
        }
        int jpn = jh*32 + ((j4 + 1) & 15)*2;
        uint4 fA1 = *(const uint4*)&ftb[((jpn + fq) & 63) << 2];
        uint4 fB1 = *(const uint4*)&ftb[((jpn + 1 + fq) & 63) << 2];

        unsigned int fl_[8] = {fA0.x, fA0.y, fA0.z, fA0.w, fB0.x, fB0.y, fB0.z, fB0.w};
        #pragma unroll
        for (int u = 0; u < 4; ++u) {
            _Float16 ah = (_Float16)fr0[u];
            half2v av = { ah, ah };
            half2v W01 = __builtin_bit_cast(half2v, tp0[u].z)*av + __builtin_bit_cast(half2v, tp0[u].x);
            half2v W23 = __builtin_bit_cast(half2v, tp0[u].w)*av + __builtin_bit_cast(half2v, tp0[u].y);
            half2v f01 = __builtin_bit_cast(half2v, fl_[u*2]);
            half2v f23 = __builtin_bit_cast(half2v, fl_[u*2+1]);
            a0 += (float)W01[0] * (float)f01[0];
            a1 += (float)W01[1] * (float)f01[1];
            a2 += (float)W23[0] * (float)f23[0];
            a3 += (float)W23[1] * (float)f23[1];
        }
        dvK = dvL;
        fr0[0]=fr1[0]; fr0[1]=fr1[1]; fr0[2]=fr1[2]; fr0[3]=fr1[3];
        tp0[0]=tp1[0]; tp0[1]=tp1[1]; tp0[2]=tp1[2]; tp0[3]=tp1[3];
        fA0 = fA1; fB0 = fB1;
    }
    // merge jh halves in-wave (partner lane = lane ^ 16), then store from jh==0 lanes
    a0 += __shfl_xor(a0, 16, 64);
    a1 += __shfl_xor(a1, 16, 64);
    a2 += __shfl_xor(a2, 16, 64);
    a3 += __shfl_xor(a3, 16, 64);
    if (jh == 0) {
        float4 acc; acc.x = a0; acc.y = a1; acc.z = a2; acc.w = a3;
        *(float4*)&y_ws[((size_t)jc*2048 + b*512 + i0 + il)*64 + fq*4] = acc;
    }
}

// final: last post-MLP + residual + readout MLP; TWO rows per wave
__global__ __launch_bounds__(512) void schnet_final(
    const float* __restrict__ x_in,
    const float* __restrict__ y_ws,
    const float* __restrict__ f2o, const float* __restrict__ f2b,
    const float* __restrict__ dw,  const float* __restrict__ db,
    const float* __restrict__ aw1, const float* __restrict__ ab1,
    const float* __restrict__ aw2, const float* __restrict__ ab2,
    float* __restrict__ out)
{
    __shared__ float lds[12544];
    const int wg = blockIdx.x, tid = threadIdx.x;
    const int wave = tid >> 6, lane = tid & 63;
    stageWT(lds, 0, f2o + 2*4096, tid);
    stageWT(lds, 4096, dw + 2*4096, tid);
    for (int s = tid; s < 4096; s += 512) {   // aw1^T duplicated to 64 rows, swizzled
        int f = s >> 6, r = s & 63;
        lds[8192 + r*64 + ((((f >> 2) + r) & 15) << 2) + (f & 3)] = aw1[f*32 + (r & 31)];
    }
    if (tid < 64) {
        lds[12288 + tid] = f2b[2*64 + tid];
        lds[12352 + tid] = db[2*64 + tid];
        lds[12416 + tid] = ab1[tid & 31];
        lds[12480 + tid] = aw2[tid & 31];
    }
    __syncthreads();
    int row0 = wg*16 + wave*2;
    size_t ro0 = (size_t)row0*64 + lane;
    size_t ro1 = ro0 + 64;
    float y0 = 0.f, y1 = 0.f;
    #pragma unroll
    for (int c = 0; c < 4; ++c) {
        y0 += y_ws[(size_t)c*131072 + ro0];
        y1 += y_ws[(size_t)c*131072 + ro1];
    }
    float z0, z1;
    matvec64x2(lds, 0, y0, y1, lane, z0, z1);
    float u0 = ssp(z0 + lds[12288 + lane]);
    float u1 = ssp(z1 + lds[12288 + lane]);
    float w0, w1;
    matvec64x2(lds, 4096, u0, u1, lane, w0, w1);
    float x0 = x_in[ro0] + (w0 + lds[12352 + lane]);
    float x1 = x_in[ro1] + (w1 + lds[12352 + lane]);
    float s0, s1;
    matvec64x2(lds, 8192, x0, x1, lane, s0, s1);
    float h0 = ssp(s0 + lds[12416 + lane]) * lds[12480 + lane];
    float h1 = ssp(s1 + lds[12416 + lane]) * lds[12480 + lane];
    #pragma unroll
    for (int m = 1; m < 64; m <<= 1) {
        h0 += __shfl_xor(h0, m, 64);
        h1 += __shfl_xor(h1, m, 64);
    }
    if (lane == 0) {
        float a = ab2[0];
        out[row0]     = a + 0.5f*h0;   // lanes duplicate the 32-dim h twice
        out[row0 + 1] = a + 0.5f*h1;
    }
}

extern "C" void kernel_launch(void* const* d_in, const int* in_sizes, int n_in,
                              void* d_out, int out_size, void* d_ws, size_t ws_size,
                              hipStream_t stream) {
    const float* emb  = (const float*)d_in[0];
    const float* dist = (const float*)d_in[1];
    const float* in2f = (const float*)d_in[2];
    const float* fw1  = (const float*)d_in[3];
    const float* fb1  = (const float*)d_in[4];
    const float* fw2  = (const float*)d_in[5];
    const float* fb2  = (const float*)d_in[6];
    const float* f2o  = (const float*)d_in[7];
    const float* f2b  = (const float*)d_in[8];
    const float* dwp  = (const float*)d_in[9];
    const float* dbp  = (const float*)d_in[10];
    const float* aw1  = (const float*)d_in[11];
    const float* ab1  = (const float*)d_in[12];
    const float* aw2  = (const float*)d_in[13];
    const float* ab2  = (const float*)d_in[14];
    float* out = (float*)d_out;
    float* ws = (float*)d_ws;
    unsigned int* Tp_g = (unsigned int*)ws;                // 3*15232 = 45696 uints
    unsigned short* f16w = (unsigned short*)(ws + 45696);  // 2048*64 f16 = 65536 float slots
    float* x_buf = ws + 45696 + 65536;                     // 131072 floats
    float* y_ws  = x_buf + 131072;                         // 4*131072 = 524288 floats

    for (int t = 0; t < 3; ++t) {
        int grid = (t == 0) ? 212 : 128;   // t=0 carries the 84 table-build/pack wgs
        hipLaunchKernelGGL(schnet_pre, dim3(grid), dim3(512), 0, stream,
            t, emb, x_buf, y_ws, in2f, fw1, fb1, fw2, fb2, f2o, f2b, dwp, dbp, f16w, Tp_g);
        hipLaunchKernelGGL(schnet_conv, dim3(512), dim3(512), 0, stream,
            dist, f16w, Tp_g + (size_t)t*TPSZ, y_ws);
    }
    hipLaunchKernelGGL(schnet_final, dim3(128), dim3(512), 0, stream,
        x_buf, y_ws, f2o, f2b, dwp, dbp, aw1, ab1, aw2, ab2, out);
}

// Round 13
// 75.043 us; speedup vs baseline: 9.2507x; 1.0951x over previous
//
#include <hip/hip_runtime.h>

#define KBIN 224      // interpolation bins
#define TSTRIDE 68    // packed-table row stride in uints
#define TPSZ  15232   // uints per packed table (= KBIN*TSTRIDE)
#define FBASE 15232   // uint index of f-chunk region in conv LDS

typedef _Float16 half2v __attribute__((ext_vector_type(2)));

__device__ __forceinline__ float ssp(float x) {
    // softplus(x) - ln2, numerically stable
    return fmaxf(x, 0.0f) + log1pf(expf(-fabsf(x))) - 0.69314718055994531f;
}

__device__ __forceinline__ float bclane(float v, int l) {
    return __builtin_bit_cast(float, __builtin_amdgcn_readlane(__builtin_bit_cast(int, v), l));
}

// out[lane] = sum_f bclane(x,f) * WT[lane][f]; WT swizzled, b128 conflict-free
__device__ __forceinline__ float matvec64(const float* __restrict__ ldsA, int base, float xv, int lane) {
    float a0 = 0.f, a1 = 0.f, a2 = 0.f, a3 = 0.f;
    #pragma unroll
    for (int gg = 0; gg < 16; ++gg) {
        const float4 w = *(const float4*)&ldsA[base + lane*64 + (((gg + lane) & 15) << 2)];
        a0 += bclane(xv, gg*4+0) * w.x;
        a1 += bclane(xv, gg*4+1) * w.y;
        a2 += bclane(xv, gg*4+2) * w.z;
        a3 += bclane(xv, gg*4+3) * w.w;
    }
    return (a0 + a1) + (a2 + a3);
}

// 2-row batched matvec (pre0 only)
__device__ __forceinline__ void matvec64x2(const float* __restrict__ ldsA, int base,
                                           float xv0, float xv1, int lane,
                                           float& o0, float& o1) {
    float a0 = 0.f, a1 = 0.f, b0 = 0.f, b1 = 0.f;
    #pragma unroll
    for (int gg = 0; gg < 16; ++gg) {
        const float4 w = *(const float4*)&ldsA[base + lane*64 + (((gg + lane) & 15) << 2)];
        a0 += bclane(xv0, gg*4+0) * w.x;
        a1 += bclane(xv0, gg*4+1) * w.y;
        a0 += bclane(xv0, gg*4+2) * w.z;
        a1 += bclane(xv0, gg*4+3) * w.w;
        b0 += bclane(xv1, gg*4+0) * w.x;
        b1 += bclane(xv1, gg*4+1) * w.y;
        b0 += bclane(xv1, gg*4+2) * w.z;
        b1 += bclane(xv1, gg*4+3) * w.w;
    }
    o0 = a0 + a1;
    o1 = b0 + b1;
}

__device__ __forceinline__ void stageWT(float* __restrict__ lds, int base, const float* __restrict__ W, int tid) {
    for (int s = tid; s < 4096; s += 512) {
        int f = s >> 6, g = s & 63;
        lds[base + g*64 + ((((f >> 2) + g) & 15) << 2) + (f & 3)] = W[s];
    }
}

// pre0: wgs 0..127: f0 = emb@in2f0 (2 rows/wave). wgs 128..211: build+pack 3 tables.
__global__ __launch_bounds__(512) void schnet_pre0(
    const float* __restrict__ emb,
    const float* __restrict__ in2f,
    const float* __restrict__ fw1, const float* __restrict__ fb1,
    const float* __restrict__ fw2, const float* __restrict__ fb2,
    unsigned short* __restrict__ f_out, unsigned int* __restrict__ Tp_g)
{
    __shared__ float lds[12544];
    const int wg = blockIdx.x, tid = threadIdx.x;
    const int wave = tid >> 6, lane = tid & 63;
    if (wg < 128) {
        stageWT(lds, 0, in2f, tid);
        __syncthreads();
        int row0 = wg*16 + wave*2;
        size_t ro0 = (size_t)row0*64 + lane;
        size_t ro1 = ro0 + 64;
        float f0, f1;
        matvec64x2(lds, 0, emb[ro0], emb[ro1], lane, f0, f1);
        f_out[ro0] = __builtin_bit_cast(unsigned short, (_Float16)f0);
        f_out[ro1] = __builtin_bit_cast(unsigned short, (_Float16)f1);
    } else {
        // table build+pack: 28 wgs per tt, 8 bins each
        int widx = wg - 128;
        int tt = widx / 28;
        int k = (widx % 28)*8 + wave;        // bin 0..223
        const float* fw1t = fw1 + tt*25*64;
        const float* fw2t = fw2 + tt*64*64;
        for (int s = tid; s < 1600; s += 512) lds[s] = fw1t[s];
        for (int s = tid; s < 4096; s += 512) lds[1600 + s] = fw2t[s];
        if (tid < 64) { lds[5696 + tid] = fb1[tt*64 + tid]; lds[5760 + tid] = fb2[tt*64 + tid]; }
        __syncthreads();
        float T2[2];
        #pragma unroll
        for (int e = 0; e < 2; ++e) {
            float dk = (float)(k + e) * (5.0f/224.0f);
            float h1 = lds[5696 + lane];
            for (int r = 0; r < 25; ++r) {
                float sr = dk - (float)r * (5.0f/24.0f);
                h1 += expf(-10.0f*sr*sr) * lds[r*64 + lane];
            }
            float u = ssp(h1);
            float T = lds[5760 + lane];
            #pragma unroll
            for (int gg = 0; gg < 64; ++gg)
                T += bclane(u, gg) * lds[1600 + gg*64 + lane];
            T2[e] = T;
        }
        float* sc = &lds[5824 + wave*128];   // wave-private scratch (same-wave rd-after-wr)
        sc[lane] = T2[0];
        sc[64 + lane] = T2[1];
        if (lane < 16) {
            float4 A  = *(const float4*)&sc[lane*4];
            float4 Bv = *(const float4*)&sc[64 + lane*4];
            half2v t01 = { (_Float16)A.x, (_Float16)A.y };
            half2v t23 = { (_Float16)A.z, (_Float16)A.w };
            half2v d01 = { (_Float16)(Bv.x - A.x), (_Float16)(Bv.y - A.y) };
            half2v d23 = { (_Float16)(Bv.z - A.z), (_Float16)(Bv.w - A.w) };
            uint4 o;
            o.x = __builtin_bit_cast(unsigned int, t01);
            o.y = __builtin_bit_cast(unsigned int, t23);
            o.z = __builtin_bit_cast(unsigned int, d01);
            o.w = __builtin_bit_cast(unsigned int, d23);
            *(uint4*)&Tp_g[(size_t)tt*TPSZ + k*TSTRIDE + lane*4] = o;
        }
    }
}

// K(t): 512 wgs = (b 4) x (it 128). Each wg: i-tile of 4 rows x ALL 512 j (4 chunks of 128),
// then row-local post-MLP (+ residual, + f_{t+1} or readout) — no cross-wg deps in-launch.
__global__ __launch_bounds__(512, 4) void schnet_block(
    int t,
    const float* __restrict__ emb, const float* __restrict__ dists,
    const float* __restrict__ in2f,
    const float* __restrict__ f2o, const float* __restrict__ f2b,
    const float* __restrict__ dw,  const float* __restrict__ db,
    const float* __restrict__ aw1, const float* __restrict__ ab1,
    const float* __restrict__ aw2, const float* __restrict__ ab2,
    const unsigned int* __restrict__ Tp_g,
    const unsigned short* __restrict__ f_in,
    unsigned short* __restrict__ f_out,
    float* __restrict__ x_buf, float* __restrict__ out)
{
    __shared__ unsigned int ldsu[FBASE + 4096];   // 77312 B -> 2 wgs/CU
    float* lds = (float*)ldsu;
    const int wg = blockIdx.x, tid = threadIdx.x;
    const int wave = tid >> 6, lane = tid & 63;
    const int b = wg >> 7, it = wg & 127;
    const int i0 = it * 4;
    const int fq = lane & 15, g = lane >> 4;
    const int r = wave >> 1;          // row within tile (0..3)
    const int jhalf = wave & 1;       // 64-j half within chunk

    // copy this block's pre-packed table
    const unsigned int* Tp = Tp_g + (size_t)t*TPSZ;
    for (int s = tid; s < TPSZ/4; s += 512)
        ((uint4*)ldsu)[s] = ((const uint4*)Tp)[s];

    const unsigned int* Tbase = ldsu + fq*4;
    const unsigned int* ftb = ldsu + FBASE + fq*256;
    const float scale = 224.0f/5.0f;
    float a0 = 0.f, a1 = 0.f, a2 = 0.f, a3 = 0.f;

    for (int c = 0; c < 4; ++c) {
        if (c) __syncthreads();       // previous chunk fully consumed
        // stage transposed f16 f-chunk (128 j x 64 f16)
        for (int s = tid; s < 2048; s += 512) {
            int j = s >> 4, fqq = s & 15;
            const unsigned int* src = (const unsigned int*)&f_in[((size_t)b*512 + c*128 + j)*64 + fqq*4];
            int jp = j >> 1;
            unsigned int* dst = &ldsu[FBASE + fqq*256 + (((jp + fqq) & 63) << 2) + (j & 1)*2];
            dst[0] = src[0]; dst[1] = src[1];
        }
        __syncthreads();              // (c==0: also covers the table copy)
        // this wave: row i0+r, j in [jhalf*64 + g*16, +16) of chunk c
        const float4* dp = (const float4*)&dists[((size_t)(b*512 + i0 + r))*512 + c*128 + jhalf*64 + g*16];
        float4 dq[4];
        #pragma unroll
        for (int q = 0; q < 4; ++q) dq[q] = dp[q];
        const int jp_base = jhalf*32 + g*8;
        #pragma unroll
        for (int j4 = 0; j4 < 4; ++j4) {
            uint4 fA = *(const uint4*)&ftb[((jp_base + j4*2 + fq) & 63) << 2];
            uint4 fB = *(const uint4*)&ftb[((jp_base + j4*2 + 1 + fq) & 63) << 2];
            float dd[4] = {dq[j4].x, dq[j4].y, dq[j4].z, dq[j4].w};
            unsigned int fl_[8] = {fA.x, fA.y, fA.z, fA.w, fB.x, fB.y, fB.z, fB.w};
            #pragma unroll
            for (int u = 0; u < 4; ++u) {
                float tv = fminf(fmaxf(dd[u], 0.0f)*scale, 223.999f);
                int k = (int)tv;
                float fr = tv - (float)k;
                uint4 tp = *(const uint4*)&Tbase[k*TSTRIDE];
                _Float16 ah = (_Float16)fr;
                half2v av = { ah, ah };
                half2v W01 = __builtin_bit_cast(half2v, tp.z)*av + __builtin_bit_cast(half2v, tp.x);
                half2v W23 = __builtin_bit_cast(half2v, tp.w)*av + __builtin_bit_cast(half2v, tp.y);
                half2v f01 = __builtin_bit_cast(half2v, fl_[u*2]);
                half2v f23 = __builtin_bit_cast(half2v, fl_[u*2+1]);
                a0 += (float)W01[0] * (float)f01[0];
                a1 += (float)W01[1] * (float)f01[1];
                a2 += (float)W23[0] * (float)f23[0];
                a3 += (float)W23[1] * (float)f23[1];
            }
        }
    }
    // reduce over g (4 sub-groups) in-wave
    a0 += __shfl_xor(a0, 16, 64); a0 += __shfl_xor(a0, 32, 64);
    a1 += __shfl_xor(a1, 16, 64); a1 += __shfl_xor(a1, 32, 64);
    a2 += __shfl_xor(a2, 16, 64); a2 += __shfl_xor(a2, 32, 64);
    a3 += __shfl_xor(a3, 16, 64); a3 += __shfl_xor(a3, 32, 64);

    __syncthreads();                  // all conv LDS reads done; regions reusable
    if (g == 0) {                     // y half-row per wave -> scratch (f-chunk region)
        float4 acc; acc.x = a0; acc.y = a1; acc.z = a2; acc.w = a3;
        *(float4*)&lds[FBASE + wave*64 + fq*4] = acc;
    }
    // stage post weights into the (now free) table region
    stageWT(lds, 0, f2o + t*4096, tid);
    stageWT(lds, 4096, dw + t*4096, tid);
    if (t < 2) {
        stageWT(lds, 8192, in2f + (t+1)*4096, tid);
    } else {
        for (int s = tid; s < 4096; s += 512) {   // aw1^T dup to 64 rows, swizzled
            int f = s >> 6, rr = s & 63;
            lds[8192 + rr*64 + ((((f >> 2) + rr) & 15) << 2) + (f & 3)] = aw1[f*32 + (rr & 31)];
        }
    }
    if (tid < 64) {
        lds[12288 + tid] = f2b[t*64 + tid];
        lds[12352 + tid] = db[t*64 + tid];
        if (t == 2) {
            lds[12416 + tid] = ab1[tid & 31];
            lds[12480 + tid] = aw2[tid & 31];
        }
    }
    __syncthreads();

    if (wave < 4) {                   // row-local post: wave w handles row i0+w
        int grow = b*512 + i0 + wave;
        size_t ro = (size_t)grow*64 + lane;
        float y = lds[FBASE + (wave*2)*64 + lane] + lds[FBASE + (wave*2+1)*64 + lane];
        float z = matvec64(lds, 0, y, lane) + lds[12288 + lane];
        float u = ssp(z);
        float y3 = matvec64(lds, 4096, u, lane) + lds[12352 + lane];
        float xin = (t == 0) ? emb[ro] : x_buf[ro];
        float xn = xin + y3;
        if (t < 2) {
            x_buf[ro] = xn;
            float fo = matvec64(lds, 8192, xn, lane);
            f_out[ro] = __builtin_bit_cast(unsigned short, (_Float16)fo);
        } else {
            float s1 = matvec64(lds, 8192, xn, lane) + lds[12416 + lane];
            float h = ssp(s1) * lds[12480 + lane];
            #pragma unroll
            for (int m = 1; m < 64; m <<= 1)
                h += __shfl_xor(h, m, 64);
            if (lane == 0) out[grow] = ab2[0] + 0.5f*h;   // lanes duplicate 32-dim h twice
        }
    }
}

extern "C" void kernel_launch(void* const* d_in, const int* in_sizes, int n_in,
                              void* d_out, int out_size, void* d_ws, size_t ws_size,
                              hipStream_t stream) {
    const float* emb  = (const float*)d_in[0];
    const float* dist = (const float*)d_in[1];
    const float* in2f = (const float*)d_in[2];
    const float* fw1  = (const float*)d_in[3];
    const float* fb1  = (const float*)d_in[4];
    const float* fw2  = (const float*)d_in[5];
    const float* fb2  = (const float*)d_in[6];
    const float* f2o  = (const float*)d_in[7];
    const float* f2b  = (const float*)d_in[8];
    const float* dwp  = (const float*)d_in[9];
    const float* dbp  = (const float*)d_in[10];
    const float* aw1  = (const float*)d_in[11];
    const float* ab1  = (const float*)d_in[12];
    const float* aw2  = (const float*)d_in[13];
    const float* ab2  = (const float*)d_in[14];
    float* out = (float*)d_out;
    float* ws = (float*)d_ws;
    unsigned int* Tp_g = (unsigned int*)ws;                  // 3*15232 = 45696 uints
    unsigned short* fA = (unsigned short*)(ws + 45696);      // 2048*64 f16 = 65536 float slots
    unsigned short* fB = (unsigned short*)(ws + 45696 + 65536);
    float* x_buf = ws + 45696 + 2*65536;                     // 131072 floats

    hipLaunchKernelGGL(schnet_pre0, dim3(212), dim3(512), 0, stream,
        emb, in2f, fw1, fb1, fw2, fb2, fA, Tp_g);
    hipLaunchKernelGGL(schnet_block, dim3(512), dim3(512), 0, stream,
        0, emb, dist, in2f, f2o, f2b, dwp, dbp, aw1, ab1, aw2, ab2,
        Tp_g, fA, fB, x_buf, out);
    hipLaunchKernelGGL(schnet_block, dim3(512), dim3(512), 0, stream,
        1, emb, dist, in2f, f2o, f2b, dwp, dbp, aw1, ab1, aw2, ab2,
        Tp_g, fB, fA, x_buf, out);
    hipLaunchKernelGGL(schnet_block, dim3(512), dim3(512), 0, stream,
        2, emb, dist, in2f, f2o, f2b, dwp, dbp, aw1, ab1, aw2, ab2,
        Tp_g, fA, fB, x_buf, out);
}

// Round 15
// 64.563 us; speedup vs baseline: 10.7523x; 1.1623x over previous
//
#include <hip/hip_runtime.h>

#define KBIN 224      // interpolation bins
#define TSTRIDE 68    // packed-table row stride in uints (272 B)
#define TPSZ  15232   // uints per packed table (= KBIN*TSTRIDE)
#define FBASE 15232   // uint index of f-chunk region in conv LDS

typedef _Float16 half2v __attribute__((ext_vector_type(2)));

__device__ __forceinline__ float ssp(float x) {
    // softplus(x) - ln2, numerically stable
    return fmaxf(x, 0.0f) + log1pf(expf(-fabsf(x))) - 0.69314718055994531f;
}

__device__ __forceinline__ float bclane(float v, int l) {
    return __builtin_bit_cast(float, __builtin_amdgcn_readlane(__builtin_bit_cast(int, v), l));
}

// pack one pair: hi16 = k*272 (byte offset into packed table), lo16 = f16 frac
__device__ __forceinline__ unsigned int kaenc(float d) {
    float tv = fminf(fmaxf(d, 0.0f)*(224.0f/5.0f), 223.999f);
    int k = (int)tv;
    float fr = tv - (float)k;
    unsigned short fh = __builtin_bit_cast(unsigned short, (_Float16)fr);
    return ((unsigned int)(k*272) << 16) | (unsigned int)fh;
}

// out[lane] = sum_f bclane(x,f) * WT[lane][f]; WT swizzled, b128 conflict-free
__device__ __forceinline__ float matvec64(const float* __restrict__ ldsA, int base, float xv, int lane) {
    float a0 = 0.f, a1 = 0.f, a2 = 0.f, a3 = 0.f;
    #pragma unroll
    for (int gg = 0; gg < 16; ++gg) {
        const float4 w = *(const float4*)&ldsA[base + lane*64 + (((gg + lane) & 15) << 2)];
        a0 += bclane(xv, gg*4+0) * w.x;
        a1 += bclane(xv, gg*4+1) * w.y;
        a2 += bclane(xv, gg*4+2) * w.z;
        a3 += bclane(xv, gg*4+3) * w.w;
    }
    return (a0 + a1) + (a2 + a3);
}

// 2-row batched matvec (pre0 only)
__device__ __forceinline__ void matvec64x2(const float* __restrict__ ldsA, int base,
                                           float xv0, float xv1, int lane,
                                           float& o0, float& o1) {
    float a0 = 0.f, a1 = 0.f, b0 = 0.f, b1 = 0.f;
    #pragma unroll
    for (int gg = 0; gg < 16; ++gg) {
        const float4 w = *(const float4*)&ldsA[base + lane*64 + (((gg + lane) & 15) << 2)];
        a0 += bclane(xv0, gg*4+0) * w.x;
        a1 += bclane(xv0, gg*4+1) * w.y;
        a0 += bclane(xv0, gg*4+2) * w.z;
        a1 += bclane(xv0, gg*4+3) * w.w;
        b0 += bclane(xv1, gg*4+0) * w.x;
        b1 += bclane(xv1, gg*4+1) * w.y;
        b0 += bclane(xv1, gg*4+2) * w.z;
        b1 += bclane(xv1, gg*4+3) * w.w;
    }
    o0 = a0 + a1;
    o1 = b0 + b1;
}

__device__ __forceinline__ void stageWT(float* __restrict__ lds, int base, const float* __restrict__ W, int tid) {
    for (int s = tid; s < 4096; s += 512) {
        int f = s >> 6, g = s & 63;
        lds[base + g*64 + ((((f >> 2) + g) & 15) << 2) + (f & 3)] = W[s];
    }
}

// pre0: wgs [0,128): f0 = emb@in2f0 (2 rows/wave).
//       wgs [128,212): build+pack 3 tables.
//       wgs [212,468): encode ka (k,frac) for all 1M pairs, 8 pairs/thread.
__global__ __launch_bounds__(512) void schnet_pre0(
    const float* __restrict__ emb, const float* __restrict__ dists,
    const float* __restrict__ in2f,
    const float* __restrict__ fw1, const float* __restrict__ fb1,
    const float* __restrict__ fw2, const float* __restrict__ fb2,
    unsigned short* __restrict__ f_out, unsigned int* __restrict__ Tp_g,
    unsigned int* __restrict__ ka)
{
    __shared__ float lds[12544];
    const int wg = blockIdx.x, tid = threadIdx.x;
    const int wave = tid >> 6, lane = tid & 63;
    if (wg < 128) {
        stageWT(lds, 0, in2f, tid);
        __syncthreads();
        int row0 = wg*16 + wave*2;
        size_t ro0 = (size_t)row0*64 + lane;
        size_t ro1 = ro0 + 64;
        float f0, f1;
        matvec64x2(lds, 0, emb[ro0], emb[ro1], lane, f0, f1);
        f_out[ro0] = __builtin_bit_cast(unsigned short, (_Float16)f0);
        f_out[ro1] = __builtin_bit_cast(unsigned short, (_Float16)f1);
    } else if (wg < 212) {
        // table build+pack: 28 wgs per tt, 8 bins each
        int widx = wg - 128;
        int tt = widx / 28;
        int k = (widx % 28)*8 + wave;        // bin 0..223
        const float* fw1t = fw1 + tt*25*64;
        const float* fw2t = fw2 + tt*64*64;
        for (int s = tid; s < 1600; s += 512) lds[s] = fw1t[s];
        for (int s = tid; s < 4096; s += 512) lds[1600 + s] = fw2t[s];
        if (tid < 64) { lds[5696 + tid] = fb1[tt*64 + tid]; lds[5760 + tid] = fb2[tt*64 + tid]; }
        __syncthreads();
        float T2[2];
        #pragma unroll
        for (int e = 0; e < 2; ++e) {
            float dk = (float)(k + e) * (5.0f/224.0f);
            float h1 = lds[5696 + lane];
            for (int r = 0; r < 25; ++r) {
                float sr = dk - (float)r * (5.0f/24.0f);
                h1 += expf(-10.0f*sr*sr) * lds[r*64 + lane];
            }
            float u = ssp(h1);
            float T = lds[5760 + lane];
            #pragma unroll
            for (int gg = 0; gg < 64; ++gg)
                T += bclane(u, gg) * lds[1600 + gg*64 + lane];
            T2[e] = T;
        }
        float* sc = &lds[5824 + wave*128];   // wave-private scratch (same-wave rd-after-wr)
        sc[lane] = T2[0];
        sc[64 + lane] = T2[1];
        if (lane < 16) {
            float4 A  = *(const float4*)&sc[lane*4];
            float4 Bv = *(const float4*)&sc[64 + lane*4];
            half2v t01 = { (_Float16)A.x, (_Float16)A.y };
            half2v t23 = { (_Float16)A.z, (_Float16)A.w };
            half2v d01 = { (_Float16)(Bv.x - A.x), (_Float16)(Bv.y - A.y) };
            half2v d23 = { (_Float16)(Bv.z - A.z), (_Float16)(Bv.w - A.w) };
            uint4 o;
            o.x = __builtin_bit_cast(unsigned int, t01);
            o.y = __builtin_bit_cast(unsigned int, t23);
            o.z = __builtin_bit_cast(unsigned int, d01);
            o.w = __builtin_bit_cast(unsigned int, d23);
            *(uint4*)&Tp_g[(size_t)tt*TPSZ + k*TSTRIDE + lane*4] = o;
        }
    } else {
        // ka encode: 256 wgs x 512 thr x 8 pairs
        size_t p = (size_t)(wg - 212)*4096 + (size_t)tid*8;
        float4 d0 = *(const float4*)&dists[p];
        float4 d1 = *(const float4*)&dists[p + 4];
        uint4 o0, o1;
        o0.x = kaenc(d0.x); o0.y = kaenc(d0.y); o0.z = kaenc(d0.z); o0.w = kaenc(d0.w);
        o1.x = kaenc(d1.x); o1.y = kaenc(d1.y); o1.z = kaenc(d1.z); o1.w = kaenc(d1.w);
        *(uint4*)&ka[p] = o0;
        *(uint4*)&ka[p + 4] = o1;
    }
}

// K(t): 512 wgs = (b 4) x (it 128). Each wg: 4 rows x ALL 512 j (4 chunks of 128),
// then row-local post-MLP (+ residual, + f_{t+1} or readout). No cross-wg deps in-launch.
__global__ __launch_bounds__(512, 4) void schnet_block(
    int t,
    const float* __restrict__ emb,
    const float* __restrict__ in2f,
    const float* __restrict__ f2o, const float* __restrict__ f2b,
    const float* __restrict__ dw,  const float* __restrict__ db,
    const float* __restrict__ aw1, const float* __restrict__ ab1,
    const float* __restrict__ aw2, const float* __restrict__ ab2,
    const unsigned int* __restrict__ Tp_g,
    const unsigned int* __restrict__ ka,
    const unsigned short* __restrict__ f_in,
    unsigned short* __restrict__ f_out,
    float* __restrict__ x_buf, float* __restrict__ out)
{
    __shared__ unsigned int ldsu[FBASE + 4096];   // 77312 B -> 2 wgs/CU
    float* lds = (float*)ldsu;
    const int wg = blockIdx.x, tid = threadIdx.x;
    const int wave = tid >> 6, lane = tid & 63;
    const int b = wg >> 7, it = wg & 127;
    const int i0 = it * 4;
    const int fq = lane & 15, g = lane >> 4;
    const int r = wave >> 1;          // row within tile (0..3)
    const int jhalf = wave & 1;       // 64-j half within chunk

    // copy this block's pre-packed table (runs before first barrier, overlaps f staging)
    const unsigned int* Tp = Tp_g + (size_t)t*TPSZ;
    for (int s = tid; s < TPSZ/4; s += 512)
        ((uint4*)ldsu)[s] = ((const uint4*)Tp)[s];

    // f staging: unit = (j0 = tid>>4 in [0,32), fq2 = tid&15); thread covers j = j0 + {0,32,64,96}.
    // Global: entry (j, fq2) = uint2 index j*16 + fq2 (row = 64 f16 = 16 uint2).
    // LDS (transposed): uint idx FBASE + (j>>1)*64 + fq2*4 + (j&1)*2  (16B entry per (jp,fq))
    const int j0 = tid >> 4, fq2 = tid & 15;
    const uint2* fsrc0 = (const uint2*)f_in + ((size_t)b*512 + j0)*16 + fq2;
    unsigned int* fdst = ldsu + FBASE + (j0 >> 1)*64 + fq2*4 + (j0 & 1)*2;
    uint2 rb0, rb1, rb2, rb3;
    // prologue: load + write chunk 0
    {
        const uint2* sp = fsrc0;                 // chunk 0
        rb0 = sp[0]; rb1 = sp[512]; rb2 = sp[1024]; rb3 = sp[1536];
        *(uint2*)fdst = rb0; *(uint2*)(fdst + 1024) = rb1;
        *(uint2*)(fdst + 2048) = rb2; *(uint2*)(fdst + 3072) = rb3;
    }
    __syncthreads();   // table + chunk 0 ready

    const unsigned int* kabase = &ka[((size_t)(b*512 + i0 + r))*512 + jhalf*64 + g*16];
    const unsigned int* fp = ldsu + FBASE + fq*4;
    const char* Tbyte = (const char*)ldsu + fq*16;
    const int jpb = jhalf*32 + g*8;
    float a0 = 0.f, a1 = 0.f, a2 = 0.f, a3 = 0.f;

    for (int c = 0; c < 4; ++c) {
        if (c < 3) {  // prefetch next chunk's f into regs (latency hides under compute)
            const uint2* sp = fsrc0 + (size_t)(c + 1)*2048;
            rb0 = sp[0]; rb1 = sp[512]; rb2 = sp[1024]; rb3 = sp[1536];
        }
        // load this row's packed (k,a) for the 16 j of this group
        uint4 kq0 = ((const uint4*)(kabase + c*128))[0];
        uint4 kq1 = ((const uint4*)(kabase + c*128))[1];
        uint4 kq2 = ((const uint4*)(kabase + c*128))[2];
        uint4 kq3 = ((const uint4*)(kabase + c*128))[3];
        uint4 kqa[4] = {kq0, kq1, kq2, kq3};
        #pragma unroll
        for (int j4 = 0; j4 < 4; ++j4) {
            uint4 fA = *(const uint4*)&fp[(jpb + j4*2)*64];
            uint4 fB = *(const uint4*)&fp[(jpb + j4*2 + 1)*64];
            unsigned int kk[4] = {kqa[j4].x, kqa[j4].y, kqa[j4].z, kqa[j4].w};
            unsigned int fl_[8] = {fA.x, fA.y, fA.z, fA.w, fB.x, fB.y, fB.z, fB.w};
            #pragma unroll
            for (int u = 0; u < 4; ++u) {
                unsigned int kau = kk[u];
                unsigned int koff = kau >> 16;
                half2v av = __builtin_bit_cast(half2v, __builtin_amdgcn_perm(kau, kau, 0x01000100u));
                uint4 tp = *(const uint4*)(Tbyte + koff);
                half2v W01 = __builtin_bit_cast(half2v, tp.z)*av + __builtin_bit_cast(half2v, tp.x);
                half2v W23 = __builtin_bit_cast(half2v, tp.w)*av + __builtin_bit_cast(half2v, tp.y);
                half2v f01 = __builtin_bit_cast(half2v, fl_[u*2]);
                half2v f23 = __builtin_bit_cast(half2v, fl_[u*2+1]);
                a0 += (float)W01[0] * (float)f01[0];
                a1 += (float)W01[1] * (float)f01[1];
                a2 += (float)W23[0] * (float)f23[0];
                a3 += (float)W23[1] * (float)f23[1];
            }
        }
        if (c < 3) {
            __syncthreads();           // all lanes done reading chunk c
            *(uint2*)fdst = rb0; *(uint2*)(fdst + 1024) = rb1;
            *(uint2*)(fdst + 2048) = rb2; *(uint2*)(fdst + 3072) = rb3;
            __syncthreads();           // chunk c+1 ready
        }
    }
    // reduce over g (4 sub-groups) in-wave
    a0 += __shfl_xor(a0, 16, 64); a0 += __shfl_xor(a0, 32, 64);
    a1 += __shfl_xor(a1, 16, 64); a1 += __shfl_xor(a1, 32, 64);
    a2 += __shfl_xor(a2, 16, 64); a2 += __shfl_xor(a2, 32, 64);
    a3 += __shfl_xor(a3, 16, 64); a3 += __shfl_xor(a3, 32, 64);

    __syncthreads();                  // all conv LDS reads done; regions reusable
    if (g == 0) {                     // y half-row per wave -> scratch (f-chunk region)
        float4 acc; acc.x = a0; acc.y = a1; acc.z = a2; acc.w = a3;
        *(float4*)&lds[FBASE + wave*64 + fq*4] = acc;
    }
    // stage post weights into the (now free) table region
    stageWT(lds, 0, f2o + t*4096, tid);
    stageWT(lds, 4096, dw + t*4096, tid);
    if (t < 2) {
        stageWT(lds, 8192, in2f + (t+1)*4096, tid);
    } else {
        for (int s = tid; s < 4096; s += 512) {   // aw1^T dup to 64 rows, swizzled
            int f = s >> 6, rr = s & 63;
            lds[8192 + rr*64 + ((((f >> 2) + rr) & 15) << 2) + (f & 3)] = aw1[f*32 + (rr & 31)];
        }
    }
    if (tid < 64) {
        lds[12288 + tid] = f2b[t*64 + tid];
        lds[12352 + tid] = db[t*64 + tid];
        if (t == 2) {
            lds[12416 + tid] = ab1[tid & 31];
            lds[12480 + tid] = aw2[tid & 31];
        }
    }
    __syncthreads();

    if (wave < 4) {                   // row-local post: wave w handles row i0+w
        int grow = b*512 + i0 + wave;
        size_t ro = (size_t)grow*64 + lane;
        float y = lds[FBASE + (wave*2)*64 + lane] + lds[FBASE + (wave*2+1)*64 + lane];
        float z = matvec64(lds, 0, y, lane) + lds[12288 + lane];
        float u = ssp(z);
        float y3 = matvec64(lds, 4096, u, lane) + lds[12352 + lane];
        float xin = (t == 0) ? emb[ro] : x_buf[ro];
        float xn = xin + y3;
        if (t < 2) {
            x_buf[ro] = xn;
            float fo = matvec64(lds, 8192, xn, lane);
            f_out[ro] = __builtin_bit_cast(unsigned short, (_Float16)fo);
        } else {
            float s1 = matvec64(lds, 8192, xn, lane) + lds[12416 + lane];
            float h = ssp(s1) * lds[12480 + lane];
            #pragma unroll
            for (int m = 1; m < 64; m <<= 1)
                h += __shfl_xor(h, m, 64);
            if (lane == 0) out[grow] = ab2[0] + 0.5f*h;   // lanes duplicate 32-dim h twice
        }
    }
}

extern "C" void kernel_launch(void* const* d_in, const int* in_sizes, int n_in,
                              void* d_out, int out_size, void* d_ws, size_t ws_size,
                              hipStream_t stream) {
    const float* emb  = (const float*)d_in[0];
    const float* dist = (const float*)d_in[1];
    const float* in2f = (const float*)d_in[2];
    const float* fw1  = (const float*)d_in[3];
    const float* fb1  = (const float*)d_in[4];
    const float* fw2  = (const float*)d_in[5];
    const float* fb2  = (const float*)d_in[6];
    const float* f2o  = (const float*)d_in[7];
    const float* f2b  = (const float*)d_in[8];
    const float* dwp  = (const float*)d_in[9];
    const float* dbp  = (const float*)d_in[10];
    const float* aw1  = (const float*)d_in[11];
    const float* ab1  = (const float*)d_in[12];
    const float* aw2  = (const float*)d_in[13];
    const float* ab2  = (const float*)d_in[14];
    float* out = (float*)d_out;
    float* ws = (float*)d_ws;
    unsigned int* Tp_g = (unsigned int*)ws;                  // 45696 uints
    unsigned short* fA = (unsigned short*)(ws + 45696);      // 65536 float slots
    unsigned short* fB = (unsigned short*)(ws + 45696 + 65536);
    float* x_buf = ws + 45696 + 2*65536;                     // 131072 floats
    unsigned int* ka = (unsigned int*)(x_buf + 131072);      // 1048576 uints (4 MB)

    hipLaunchKernelGGL(schnet_pre0, dim3(468), dim3(512), 0, stream,
        emb, dist, in2f, fw1, fb1, fw2, fb2, fA, Tp_g, ka);
    hipLaunchKernelGGL(schnet_block, dim3(512), dim3(512), 0, stream,
        0, emb, in2f, f2o, f2b, dwp, dbp, aw1, ab1, aw2, ab2,
        Tp_g, ka, fA, fB, x_buf, out);
    hipLaunchKernelGGL(schnet_block, dim3(512), dim3(512), 0, stream,
        1, emb, in2f, f2o, f2b, dwp, dbp, aw1, ab1, aw2, ab2,
        Tp_g, ka, fB, fA, x_buf, out);
    hipLaunchKernelGGL(schnet_block, dim3(512), dim3(512), 0, stream,
        2, emb, in2f, f2o, f2b, dwp, dbp, aw1, ab1, aw2, ab2,
        Tp_g, ka, fA, fB, x_buf, out);
}